// Round 9
// baseline (247.364 us; speedup 1.0000x reference)
//
#include <hip/hip_runtime.h>

// ArtNetwork: y = sigmoid(Wout @ tanh(W8 @ ... tanh(W1 @ tanh(Win@x+b)) ...))
// Design (R9) = R6 (best-known, 132.5us) + two low-risk tweaks:
//  (a) 4 tiles (64 pts) per wave-iter -> 4 independent MFMA->exp2 chains per
//      layer to fill the trans pipe / hide latency (R6 had ~13% wall-vs-busy gap);
//  (b) ONE v_rcp_f32 per 8 activations (product tree over both tiles of a pair;
//      d<=2982 -> 8-product <=6.3e27, safe) vs R6's per-4: -9 rcp/32pts.
//  Core R6 structure (validated): propagate v = 1/(1+exp2(y)); tanh = 1-2v
//  folded into next layer via A=-2*K2*W and C-operand = K2*rowsum(W). All
//  layers (input/hidden/output) as v_mfma_f32_16x16x16_f16; C/D layout == B
//  layout so MFMA out -> v8s -> next B frag. No LDS, no shuffles in loop.
//  Straight-line scalar f32 activation code (no arrays -> no compiler bloat;
//  R8 lesson). Epilogue: sigmoid with shared rcp per 6 values (R6 code x2).

typedef float  f32x4 __attribute__((ext_vector_type(4)));
typedef __fp16 f16x4 __attribute__((ext_vector_type(4)));
typedef __fp16 f16x2 __attribute__((ext_vector_type(2)));

#define K2   2.8853900817779268f    // 2*log2(e): exp2(K2*z) = e^{2z}
#define KOUT (-1.4426950408889634f) // -log2(e):  exp2(KOUT*z) = e^{-z}

// v_i = 1/(1+exp2(y_i)) for 8 values (two MFMA accs), ONE rcp, straight-line.
__device__ __forceinline__ void v8s(f32x4 ya, f32x4 yb, f16x4* oa, f16x4* ob) {
    float e0 = __builtin_amdgcn_exp2f(ya[0]);
    float e1 = __builtin_amdgcn_exp2f(ya[1]);
    float e2 = __builtin_amdgcn_exp2f(ya[2]);
    float e3 = __builtin_amdgcn_exp2f(ya[3]);
    float e4 = __builtin_amdgcn_exp2f(yb[0]);
    float e5 = __builtin_amdgcn_exp2f(yb[1]);
    float e6 = __builtin_amdgcn_exp2f(yb[2]);
    float e7 = __builtin_amdgcn_exp2f(yb[3]);
    float d0 = e0 + 1.0f, d1 = e1 + 1.0f, d2 = e2 + 1.0f, d3 = e3 + 1.0f;
    float d4 = e4 + 1.0f, d5 = e5 + 1.0f, d6 = e6 + 1.0f, d7 = e7 + 1.0f;
    float m01 = d0 * d1, m23 = d2 * d3, m45 = d4 * d5, m67 = d6 * d7;
    float mA = m01 * m23, mB = m45 * m67;          // <= 7.9e13
    float r  = __builtin_amdgcn_rcpf(mA * mB);     // <= 6.3e27, safe
    float iA = r * mB, iB = r * mA;                // 1/mA, 1/mB
    float i01 = iA * m23, i23 = iA * m01;
    float i45 = iB * m67, i67 = iB * m45;
    float v0 = i01 * d1, v1 = i01 * d0;
    float v2 = i23 * d3, v3 = i23 * d2;
    float v4 = i45 * d5, v5 = i45 * d4;
    float v6 = i67 * d7, v7 = i67 * d6;
    f16x2 a01 = __builtin_amdgcn_cvt_pkrtz(v0, v1);
    f16x2 a23 = __builtin_amdgcn_cvt_pkrtz(v2, v3);
    f16x2 b01 = __builtin_amdgcn_cvt_pkrtz(v4, v5);
    f16x2 b23 = __builtin_amdgcn_cvt_pkrtz(v6, v7);
    *oa = __builtin_shufflevector(a01, a23, 0, 1, 2, 3);
    *ob = __builtin_shufflevector(b01, b23, 0, 1, 2, 3);
}

__global__ __launch_bounds__(256, 8)
void artnet_kernel(const float2* __restrict__ x,     // [N][2]
                   const float2* __restrict__ Win,   // [16][2]
                   const float*  __restrict__ bin,   // [16]
                   const float4* __restrict__ Wh,    // [8][16][16]
                   const float4* __restrict__ Wout,  // [3][16]
                   float* __restrict__ out,          // [N][3]
                   int nQuads, int nWaves)
{
    const int tid  = blockIdx.x * 256 + threadIdx.x;
    const int gw   = tid >> 6;            // global wave id
    const int lane = threadIdx.x & 63;
    const int row  = lane & 15;           // m / point-col index
    const int quad = lane >> 4;           // 0..3

    // ---- Hidden layers: A = -2*K2*W (f16), C = K2*rowsum(W) (f32, by C/D row)
    f16x4 aw[8];
    f32x4 crs[8];
#pragma unroll
    for (int l = 0; l < 8; ++l) {
        float4 w = Wh[l * 64 + row * 4 + quad];
        const float s = -2.0f * K2;
        f16x2 lo = __builtin_amdgcn_cvt_pkrtz(w.x * s, w.y * s);
        f16x2 hi = __builtin_amdgcn_cvt_pkrtz(w.z * s, w.w * s);
        aw[l] = __builtin_shufflevector(lo, hi, 0, 1, 2, 3);
        float partial = w.x + w.y + w.z + w.w;
        partial += __shfl_xor(partial, 16, 64);
        partial += __shfl_xor(partial, 32, 64);   // all quads of this row agree
        f32x4 c;
#pragma unroll
        for (int i = 0; i < 4; ++i)
            c[i] = K2 * __shfl(partial, quad * 4 + i, 64);
        crs[l] = c;
    }

    // ---- Input layer: A[m=row][k] = {K2*Win.x, K2*Win.y, K2*b, 0} on quad 0
    f16x4 awin = {(__fp16)0.0f, (__fp16)0.0f, (__fp16)0.0f, (__fp16)0.0f};
    if (quad == 0) {
        float2 wr = Win[row];
        f16x2 lo = __builtin_amdgcn_cvt_pkrtz(wr.x * K2, wr.y * K2);
        f16x2 hi = __builtin_amdgcn_cvt_pkrtz(bin[row] * K2, 0.0f);
        awin = __builtin_shufflevector(lo, hi, 0, 1, 2, 3);
    }

    // ---- Output layer: A = -2*KOUT*Wout (rows 0..2), C = KOUT*rowsum(Wout)
    f16x4 awo = {(__fp16)0.0f, (__fp16)0.0f, (__fp16)0.0f, (__fp16)0.0f};
    float prt = 0.0f;
    if (row < 3) {
        float4 w = Wout[row * 4 + quad];
        const float s = -2.0f * KOUT;
        f16x2 lo = __builtin_amdgcn_cvt_pkrtz(w.x * s, w.y * s);
        f16x2 hi = __builtin_amdgcn_cvt_pkrtz(w.z * s, w.w * s);
        awo = __builtin_shufflevector(lo, hi, 0, 1, 2, 3);
        prt = w.x + w.y + w.z + w.w;
    }
    prt += __shfl_xor(prt, 16, 64);
    prt += __shfl_xor(prt, 32, 64);
    f32x4 crso;
#pragma unroll
    for (int i = 0; i < 4; ++i)
        crso[i] = KOUT * __shfl(prt, quad * 4 + i, 64);

    const f32x4 zero4 = {0.0f, 0.0f, 0.0f, 0.0f};
    const f16x2 one0  = {(__fp16)1.0f, (__fp16)0.0f};

    for (int pi = gw; pi < nQuads; pi += nWaves) {
        const int t0 = pi * 4;           // first tile of the quad-group
        f16x4 bf[4];
        f32x4 acco[4];

        // ---- Input layer via MFMA: B = {x, y, 1, *}; quad>0 is don't-care.
#pragma unroll
        for (int s = 0; s < 4; ++s) {
            float2 xv = x[(t0 + s) * 16 + row];
            f16x2 lo = __builtin_amdgcn_cvt_pkrtz(xv.x, xv.y);
            bf[s] = __builtin_shufflevector(lo, one0, 0, 1, 2, 3);
        }
        {
            f32x4 a0 = __builtin_amdgcn_mfma_f32_16x16x16f16(awin, bf[0], zero4, 0, 0, 0);
            f32x4 a1 = __builtin_amdgcn_mfma_f32_16x16x16f16(awin, bf[1], zero4, 0, 0, 0);
            f32x4 a2 = __builtin_amdgcn_mfma_f32_16x16x16f16(awin, bf[2], zero4, 0, 0, 0);
            f32x4 a3 = __builtin_amdgcn_mfma_f32_16x16x16f16(awin, bf[3], zero4, 0, 0, 0);
            v8s(a0, a1, &bf[0], &bf[1]);
            v8s(a2, a3, &bf[2], &bf[3]);
        }

        // ---- 8 hidden layers: 4 MFMA -> 2x v8s -> next B frags
#pragma unroll
        for (int l = 0; l < 8; ++l) {
            f32x4 a0 = __builtin_amdgcn_mfma_f32_16x16x16f16(aw[l], bf[0], crs[l], 0, 0, 0);
            f32x4 a1 = __builtin_amdgcn_mfma_f32_16x16x16f16(aw[l], bf[1], crs[l], 0, 0, 0);
            f32x4 a2 = __builtin_amdgcn_mfma_f32_16x16x16f16(aw[l], bf[2], crs[l], 0, 0, 0);
            f32x4 a3 = __builtin_amdgcn_mfma_f32_16x16x16f16(aw[l], bf[3], crs[l], 0, 0, 0);
            v8s(a0, a1, &bf[0], &bf[1]);
            v8s(a2, a3, &bf[2], &bf[3]);
        }

        // ---- Output MFMA: quad-0 lanes hold KOUT*zout in acc[0..2]
#pragma unroll
        for (int s = 0; s < 4; ++s)
            acco[s] = __builtin_amdgcn_mfma_f32_16x16x16f16(awo, bf[s], crso, 0, 0, 0);

        // ---- Sigmoid epilogue (R6 code, applied per tile-pair)
        if (quad == 0) {
#pragma unroll
            for (int g = 0; g < 2; ++g) {
                f32x4 A = acco[g * 2 + 0];
                f32x4 B = acco[g * 2 + 1];
                float ea0 = __builtin_amdgcn_exp2f(A[0]);
                float ea1 = __builtin_amdgcn_exp2f(A[1]);
                float ea2 = __builtin_amdgcn_exp2f(A[2]);
                float eb0 = __builtin_amdgcn_exp2f(B[0]);
                float eb1 = __builtin_amdgcn_exp2f(B[1]);
                float eb2 = __builtin_amdgcn_exp2f(B[2]);
                float da0 = ea0 + 1.0f, da1 = ea1 + 1.0f, da2 = ea2 + 1.0f;
                float db0 = eb0 + 1.0f, db1 = eb1 + 1.0f, db2 = eb2 + 1.0f;
                float pa01 = da0 * da1, P3a = pa01 * da2;   // d <= 56
                float pb01 = db0 * db1, P3b = pb01 * db2;
                float r  = __builtin_amdgcn_rcpf(P3a * P3b);
                float rA = r * P3b, rB = r * P3a;
                float sa2 = rA * pa01;
                float ia  = rA * da2;
                float sa0 = ia * da1, sa1 = ia * da0;
                float sb2 = rB * pb01;
                float ib  = rB * db2;
                float sb0 = ib * db1, sb1 = ib * db0;
                const int p0 = (t0 + g * 2) * 16 + row;
                out[p0 * 3 + 0] = sa0;
                out[p0 * 3 + 1] = sa1;
                out[p0 * 3 + 2] = sa2;
                const int p1 = p0 + 16;
                out[p1 * 3 + 0] = sb0;
                out[p1 * 3 + 1] = sb1;
                out[p1 * 3 + 2] = sb2;
            }
        }
    }
}

extern "C" void kernel_launch(void* const* d_in, const int* in_sizes, int n_in,
                              void* d_out, int out_size, void* d_ws, size_t ws_size,
                              hipStream_t stream) {
    const float2* x    = (const float2*)d_in[0];
    const float2* Win  = (const float2*)d_in[1];
    const float*  bin  = (const float*) d_in[2];
    const float4* Wh   = (const float4*)d_in[3];
    const float4* Wout = (const float4*)d_in[4];
    float* out = (float*)d_out;

    const int n      = in_sizes[0] / 2;   // 4,194,304 points
    const int nQuads = n / 64;            // 4 tiles of 16 points per wave-iter
    const int blocks = 4096;              // 16384 waves, 4 iters/wave, no tail
    const int nWaves = blocks * 4;

    artnet_kernel<<<blocks, 256, 0, stream>>>(x, Win, bin, Wh, Wout, out, nQuads, nWaves);
}

// Round 10
// 197.029 us; speedup vs baseline: 1.2555x; 1.2555x over previous
//
#include <hip/hip_runtime.h>

// ArtNetwork: y = sigmoid(Wout @ tanh(W8 @ ... tanh(W1 @ tanh(Win@x+b)) ...))
// Design (R10) = R6 (best-known, 132.5us) + ONE isolated tweak:
//   v4s -> v8s: ONE v_rcp_f32 per 8 activations (product tree spanning both
//   tiles; d<=2982 -> total product <=6.3e27, safe in f32). -9 rcp/iter.
//   R9's 4-tile variant spilled (FETCH/WRITE exploded 16/49 -> 250/247 MB under
//   the 8-waves/EU VGPR cap); tile count stays at 2, launch_bounds stays (256,6).
//  Core R6 structure (validated): propagate v = 1/(1+exp2(y)); tanh = 1-2v
//  folded into next layer via A=-2*K2*W and C-operand = K2*rowsum(W). All
//  layers (input/hidden/output) as v_mfma_f32_16x16x16_f16; C/D layout == B
//  layout so MFMA out -> v8s -> next B frag. No LDS, no shuffles in loop.
//  Straight-line scalar f32 activation code (R8 lesson: no arrays).

typedef float  f32x4 __attribute__((ext_vector_type(4)));
typedef __fp16 f16x4 __attribute__((ext_vector_type(4)));
typedef __fp16 f16x2 __attribute__((ext_vector_type(2)));

#define K2   2.8853900817779268f    // 2*log2(e): exp2(K2*z) = e^{2z}
#define KOUT (-1.4426950408889634f) // -log2(e):  exp2(KOUT*z) = e^{-z}

// v_i = 1/(1+exp2(y_i)) for 8 values (two MFMA accs), ONE rcp, straight-line.
__device__ __forceinline__ void v8s(f32x4 ya, f32x4 yb, f16x4* oa, f16x4* ob) {
    float e0 = __builtin_amdgcn_exp2f(ya[0]);
    float e1 = __builtin_amdgcn_exp2f(ya[1]);
    float e2 = __builtin_amdgcn_exp2f(ya[2]);
    float e3 = __builtin_amdgcn_exp2f(ya[3]);
    float e4 = __builtin_amdgcn_exp2f(yb[0]);
    float e5 = __builtin_amdgcn_exp2f(yb[1]);
    float e6 = __builtin_amdgcn_exp2f(yb[2]);
    float e7 = __builtin_amdgcn_exp2f(yb[3]);
    float d0 = e0 + 1.0f, d1 = e1 + 1.0f, d2 = e2 + 1.0f, d3 = e3 + 1.0f;
    float d4 = e4 + 1.0f, d5 = e5 + 1.0f, d6 = e6 + 1.0f, d7 = e7 + 1.0f;
    float m01 = d0 * d1, m23 = d2 * d3, m45 = d4 * d5, m67 = d6 * d7;
    float mA = m01 * m23, mB = m45 * m67;          // <= 7.9e13 each
    float r  = __builtin_amdgcn_rcpf(mA * mB);     // <= 6.3e27, fits f32
    float iA = r * mB, iB = r * mA;                // 1/mA, 1/mB
    float i01 = iA * m23, i23 = iA * m01;
    float i45 = iB * m67, i67 = iB * m45;
    float v0 = i01 * d1, v1 = i01 * d0;
    float v2 = i23 * d3, v3 = i23 * d2;
    float v4 = i45 * d5, v5 = i45 * d4;
    float v6 = i67 * d7, v7 = i67 * d6;
    f16x2 a01 = __builtin_amdgcn_cvt_pkrtz(v0, v1);
    f16x2 a23 = __builtin_amdgcn_cvt_pkrtz(v2, v3);
    f16x2 b01 = __builtin_amdgcn_cvt_pkrtz(v4, v5);
    f16x2 b23 = __builtin_amdgcn_cvt_pkrtz(v6, v7);
    *oa = __builtin_shufflevector(a01, a23, 0, 1, 2, 3);
    *ob = __builtin_shufflevector(b01, b23, 0, 1, 2, 3);
}

__global__ __launch_bounds__(256, 6)
void artnet_kernel(const float2* __restrict__ x,     // [N][2]
                   const float2* __restrict__ Win,   // [16][2]
                   const float*  __restrict__ bin,   // [16]
                   const float4* __restrict__ Wh,    // [8][16][16]
                   const float4* __restrict__ Wout,  // [3][16]
                   float* __restrict__ out,          // [N][3]
                   int nPairs, int nWaves)
{
    const int tid  = blockIdx.x * 256 + threadIdx.x;
    const int gw   = tid >> 6;            // global wave id
    const int lane = threadIdx.x & 63;
    const int row  = lane & 15;           // m / point-col index
    const int quad = lane >> 4;           // 0..3

    // ---- Hidden layers: A = -2*K2*W (f16), C = K2*rowsum(W) (f32, by C/D row)
    f16x4 aw[8];
    f32x4 crs[8];
#pragma unroll
    for (int l = 0; l < 8; ++l) {
        float4 w = Wh[l * 64 + row * 4 + quad];
        const float s = -2.0f * K2;
        f16x2 lo = __builtin_amdgcn_cvt_pkrtz(w.x * s, w.y * s);
        f16x2 hi = __builtin_amdgcn_cvt_pkrtz(w.z * s, w.w * s);
        aw[l] = __builtin_shufflevector(lo, hi, 0, 1, 2, 3);
        float partial = w.x + w.y + w.z + w.w;
        partial += __shfl_xor(partial, 16, 64);
        partial += __shfl_xor(partial, 32, 64);   // all quads of this row agree
        f32x4 c;
#pragma unroll
        for (int i = 0; i < 4; ++i)
            c[i] = K2 * __shfl(partial, quad * 4 + i, 64);
        crs[l] = c;
    }

    // ---- Input layer: A[m=row][k] = {K2*Win.x, K2*Win.y, K2*b, 0} on quad 0
    f16x4 awin = {(__fp16)0.0f, (__fp16)0.0f, (__fp16)0.0f, (__fp16)0.0f};
    if (quad == 0) {
        float2 wr = Win[row];
        f16x2 lo = __builtin_amdgcn_cvt_pkrtz(wr.x * K2, wr.y * K2);
        f16x2 hi = __builtin_amdgcn_cvt_pkrtz(bin[row] * K2, 0.0f);
        awin = __builtin_shufflevector(lo, hi, 0, 1, 2, 3);
    }

    // ---- Output layer: A = -2*KOUT*Wout (rows 0..2), C = KOUT*rowsum(Wout)
    f16x4 awo = {(__fp16)0.0f, (__fp16)0.0f, (__fp16)0.0f, (__fp16)0.0f};
    float prt = 0.0f;
    if (row < 3) {
        float4 w = Wout[row * 4 + quad];
        const float s = -2.0f * KOUT;
        f16x2 lo = __builtin_amdgcn_cvt_pkrtz(w.x * s, w.y * s);
        f16x2 hi = __builtin_amdgcn_cvt_pkrtz(w.z * s, w.w * s);
        awo = __builtin_shufflevector(lo, hi, 0, 1, 2, 3);
        prt = w.x + w.y + w.z + w.w;
    }
    prt += __shfl_xor(prt, 16, 64);
    prt += __shfl_xor(prt, 32, 64);
    f32x4 crso;
#pragma unroll
    for (int i = 0; i < 4; ++i)
        crso[i] = KOUT * __shfl(prt, quad * 4 + i, 64);

    const f32x4 zero4 = {0.0f, 0.0f, 0.0f, 0.0f};
    const f16x2 one0  = {(__fp16)1.0f, (__fp16)0.0f};

    for (int pi = gw; pi < nPairs; pi += nWaves) {
        const int t0 = pi * 2;           // first tile of the pair
        f16x4 bf[2];
        f32x4 acco[2];

        // ---- Input layer via MFMA: B = {x, y, 1, *}; quad>0 is don't-care.
#pragma unroll
        for (int s = 0; s < 2; ++s) {
            float2 xv = x[(t0 + s) * 16 + row];
            f16x2 lo = __builtin_amdgcn_cvt_pkrtz(xv.x, xv.y);
            bf[s] = __builtin_shufflevector(lo, one0, 0, 1, 2, 3);
        }
        {
            f32x4 a0 = __builtin_amdgcn_mfma_f32_16x16x16f16(awin, bf[0], zero4, 0, 0, 0);
            f32x4 a1 = __builtin_amdgcn_mfma_f32_16x16x16f16(awin, bf[1], zero4, 0, 0, 0);
            v8s(a0, a1, &bf[0], &bf[1]);
        }

        // ---- 8 hidden layers: 2 MFMA -> v8s (one rcp) -> next B frags
#pragma unroll
        for (int l = 0; l < 8; ++l) {
            f32x4 a0 = __builtin_amdgcn_mfma_f32_16x16x16f16(aw[l], bf[0], crs[l], 0, 0, 0);
            f32x4 a1 = __builtin_amdgcn_mfma_f32_16x16x16f16(aw[l], bf[1], crs[l], 0, 0, 0);
            v8s(a0, a1, &bf[0], &bf[1]);
        }

        // ---- Output MFMA: quad-0 lanes hold KOUT*zout in acc[0..2]
#pragma unroll
        for (int s = 0; s < 2; ++s)
            acco[s] = __builtin_amdgcn_mfma_f32_16x16x16f16(awo, bf[s], crso, 0, 0, 0);

        // ---- Sigmoid epilogue: one rcp across 6 values (2 tiles x 3 channels)
        if (quad == 0) {
            float ea0 = __builtin_amdgcn_exp2f(acco[0][0]);
            float ea1 = __builtin_amdgcn_exp2f(acco[0][1]);
            float ea2 = __builtin_amdgcn_exp2f(acco[0][2]);
            float eb0 = __builtin_amdgcn_exp2f(acco[1][0]);
            float eb1 = __builtin_amdgcn_exp2f(acco[1][1]);
            float eb2 = __builtin_amdgcn_exp2f(acco[1][2]);
            float da0 = ea0 + 1.0f, da1 = ea1 + 1.0f, da2 = ea2 + 1.0f;
            float db0 = eb0 + 1.0f, db1 = eb1 + 1.0f, db2 = eb2 + 1.0f;
            float pa01 = da0 * da1, P3a = pa01 * da2;   // d <= 56: P6 <= 3.1e10
            float pb01 = db0 * db1, P3b = pb01 * db2;
            float r  = __builtin_amdgcn_rcpf(P3a * P3b);
            float rA = r * P3b, rB = r * P3a;           // 1/P3a, 1/P3b
            float sa2 = rA * pa01;                      // 1/da2
            float ia  = rA * da2;                       // 1/(da0*da1)
            float sa0 = ia * da1, sa1 = ia * da0;
            float sb2 = rB * pb01;
            float ib  = rB * db2;
            float sb0 = ib * db1, sb1 = ib * db0;
            const int p0 = t0 * 16 + row;
            out[p0 * 3 + 0] = sa0;
            out[p0 * 3 + 1] = sa1;
            out[p0 * 3 + 2] = sa2;
            const int p1 = p0 + 16;
            out[p1 * 3 + 0] = sb0;
            out[p1 * 3 + 1] = sb1;
            out[p1 * 3 + 2] = sb2;
        }
    }
}

extern "C" void kernel_launch(void* const* d_in, const int* in_sizes, int n_in,
                              void* d_out, int out_size, void* d_ws, size_t ws_size,
                              hipStream_t stream) {
    const float2* x    = (const float2*)d_in[0];
    const float2* Win  = (const float2*)d_in[1];
    const float*  bin  = (const float*) d_in[2];
    const float4* Wh   = (const float4*)d_in[3];
    const float4* Wout = (const float4*)d_in[4];
    float* out = (float*)d_out;

    const int n      = in_sizes[0] / 2;   // 4,194,304 points
    const int nPairs = n / 32;            // 2 tiles of 16 points per wave-iter
    const int blocks = 4096;              // 16384 waves, 8 iters/wave, no tail
    const int nWaves = blocks * 4;

    artnet_kernel<<<blocks, 256, 0, stream>>>(x, Win, bin, Wh, Wout, out, nPairs, nWaves);
}